// Round 4
// baseline (22182.195 us; speedup 1.0000x reference)
//
#include <hip/hip_runtime.h>
#include <math.h>

#define Bv 64
#define Tv 1024
#define INv 256
#define Hv 512

__device__ __forceinline__ float sigmoidf_(float x) {
    return 1.0f / (1.0f + __expf(-x));
}
__device__ __forceinline__ float tanhf_(float x) {
    float e2 = __expf(-2.0f * fabsf(x));
    float t = (1.0f - e2) / (1.0f + e2);
    return x >= 0.0f ? t : -t;
}

// Zero the per-producer flag slots through the coherence point (MALL), so the
// spin loop's cache-bypassing loads can never observe the 0xAA poison.
__global__ void kzero(unsigned* f) {
    __hip_atomic_store(&f[threadIdx.x], 0u, __ATOMIC_RELAXED, __HIP_MEMORY_SCOPE_AGENT);
}

// Persistent LSTM kernel. Grid: 256 blocks (4 batch-groups x 64 unit-groups), 512 threads.
// Each block owns 16 batches x 8 hidden units (=32 gate rows). W slices live in registers.
// Cross-block h exchange via MALL with RELAXED agent atomics (no L2 flush/inv).
// __launch_bounds__(512, 2): VGPR cap 256 — round-2's cap was 128 and spilled
// ~60 dwords/thread/step (the 32 GB WRITE_SIZE). b-loops split 2x8 to halve temps.
__global__ void __launch_bounds__(512, 2)
lstm_persist(const float* __restrict__ x, const float* __restrict__ h0,
             const float* __restrict__ c0, const float* __restrict__ W_ih,
             const float* __restrict__ W_hh, const float* __restrict__ b_ih,
             const float* __restrict__ b_hh, float* __restrict__ out,
             unsigned* __restrict__ flags, float* __restrict__ hx)
{
    const int tid = threadIdx.x;
    const int bb  = blockIdx.x >> 6;   // batch group 0..3 (16 batches each)
    const int jj  = blockIdx.x & 63;   // unit group 0..63 (8 units each)
    const int lg  = tid >> 4;          // local gate row 0..31
    const int kc  = tid & 15;          // k-chunk 0..15

    const int gate = lg >> 3, ju = lg & 7;
    const int row_g = gate * Hv + jj * 8 + ju;   // global gate row in [0,2048)

    __shared__ float xs[16 * 320];    // x tile: [b][kc*20 + i], chunk 16 + pad 4
    __shared__ float hsh[16 * 576];   // h tile: [b][kc*36 + i], chunk 32 + pad 4
    __shared__ float gts[16 * 33];    // reduced gates [b][lg]

    // Persistent weight slices in registers
    float whh[32], wih[16];
#pragma unroll
    for (int q = 0; q < 8; ++q) {
        float4 v = *(const float4*)(W_hh + (size_t)row_g * Hv + kc * 32 + q * 4);
        whh[q*4+0] = v.x; whh[q*4+1] = v.y; whh[q*4+2] = v.z; whh[q*4+3] = v.w;
    }
#pragma unroll
    for (int q = 0; q < 4; ++q) {
        float4 v = *(const float4*)(W_ih + (size_t)row_g * INv + kc * 16 + q * 4);
        wih[q*4+0] = v.x; wih[q*4+1] = v.y; wih[q*4+2] = v.z; wih[q*4+3] = v.w;
    }
    const float bias = b_ih[row_g] + b_hh[row_g];

    // Cell-state registers for the update threads (tid < 128): 16 b x 8 j
    const int ub = tid >> 3, uj = tid & 7;
    const int ubg = bb * 16 + ub, ujg = jj * 8 + uj;
    float creg = 0.0f;
    if (tid < 128) creg = c0[ubg * Hv + ujg];

    float* hT = out + (size_t)Bv * Tv * Hv;
    float* cT = hT + (size_t)Bv * Hv;

    for (int t = 0; t < Tv; ++t) {
        // ---- stage x tile (independent of h(t-1)) — plain cached loads ----
#pragma unroll
        for (int r = 0; r < 2; ++r) {
            int f = tid + r * 512;
            int b = f >> 6, i4 = f & 63;
            float4 v = *(const float4*)(x + ((size_t)(bb*16 + b) * Tv + t) * INv + i4 * 4);
            *(float4*)(&xs[b * 320 + (i4 >> 2) * 20 + (i4 & 3) * 4]) = v;
        }
        __syncthreads();

        float acc[16];
#pragma unroll
        for (int b = 0; b < 16; ++b) acc[b] = 0.0f;

        // x-projection (K = 16 cols per thread), b in two 8-wide halves
#pragma unroll
        for (int h8 = 0; h8 < 2; ++h8) {
#pragma unroll
            for (int i4 = 0; i4 < 4; ++i4) {
#pragma unroll
                for (int b8 = 0; b8 < 8; ++b8) {
                    const int b = h8 * 8 + b8;
                    float4 v = *(const float4*)(&xs[b * 320 + kc * 20 + i4 * 4]);
                    acc[b] += v.x*wih[i4*4+0] + v.y*wih[i4*4+1] + v.z*wih[i4*4+2] + v.w*wih[i4*4+3];
                }
            }
        }

        // ---- wait for all 64 producers of h(t-1): 64 lanes poll 64 flag slots ----
        if (t > 0) {
            if (tid < 64) {
                const unsigned* fp = flags + bb * 64 + tid;
                unsigned spins = 0;
                for (;;) {
                    unsigned v = __hip_atomic_load(fp, __ATOMIC_RELAXED, __HIP_MEMORY_SCOPE_AGENT);
                    if (__all(v >= (unsigned)t)) break;
                    if (++spins > (1u << 18)) break;   // fail loud, not hung
                }
            }
        }
        __syncthreads();

        // ---- stage h(t-1) tile: 16 rows x 512, via MALL (8B cache-bypassing loads) ----
        if (t == 0) {
#pragma unroll
            for (int r = 0; r < 4; ++r) {
                int f = tid + r * 512;
                int b = f >> 7, i4 = f & 127;
                float4 v = *(const float4*)(h0 + (size_t)(bb*16 + b) * Hv + i4 * 4);
                *(float4*)(&hsh[b * 576 + (i4 >> 3) * 36 + (i4 & 7) * 4]) = v;
            }
        } else {
            const float* hb = hx + ((size_t)((t - 1) & 1)) * (Bv * Hv) + (size_t)(bb * 16) * Hv;
#pragma unroll
            for (int it = 0; it < 8; ++it) {
                int f = tid + it * 512;
                int r = f >> 8, cp = f & 255;      // row, col-pair
                unsigned long long v = __hip_atomic_load(
                    (const unsigned long long*)(hb + r * Hv + cp * 2),
                    __ATOMIC_RELAXED, __HIP_MEMORY_SCOPE_AGENT);
                float lo = __uint_as_float((unsigned)v);
                float hi = __uint_as_float((unsigned)(v >> 32));
                *(float2*)(&hsh[r * 576 + (cp >> 4) * 36 + (cp & 15) * 2]) = make_float2(lo, hi);
            }
        }
        __syncthreads();

        // recurrent part (K = 32 cols per thread), b in two 8-wide halves
#pragma unroll
        for (int h8 = 0; h8 < 2; ++h8) {
#pragma unroll
            for (int i4 = 0; i4 < 8; ++i4) {
#pragma unroll
                for (int b8 = 0; b8 < 8; ++b8) {
                    const int b = h8 * 8 + b8;
                    float4 v = *(const float4*)(&hsh[b * 576 + kc * 36 + i4 * 4]);
                    acc[b] += v.x*whh[i4*4+0] + v.y*whh[i4*4+1] + v.z*whh[i4*4+2] + v.w*whh[i4*4+3];
                }
            }
        }

        // reduce partial dots across the 16 k-chunks (lane bits 0..3)
#pragma unroll
        for (int m = 1; m <= 8; m <<= 1) {
#pragma unroll
            for (int b = 0; b < 16; ++b) acc[b] += __shfl_xor(acc[b], m, 64);
        }
        if (kc == 0) {
#pragma unroll
            for (int b = 0; b < 16; ++b) gts[b * 33 + lg] = acc[b] + bias;
        }
        __syncthreads();

        // gate nonlinearities + state update (torch gate order i,f,g,o)
        if (tid < 128) {
            float gi = gts[ub * 33 +      uj];
            float gf = gts[ub * 33 +  8 + uj];
            float gg = gts[ub * 33 + 16 + uj];
            float go = gts[ub * 33 + 24 + uj];
            float iv = sigmoidf_(gi), fv = sigmoidf_(gf);
            float gv = tanhf_(gg),    ov = sigmoidf_(go);
            creg = fv * creg + iv * gv;
            float hv = ov * tanhf_(creg);
            out[((size_t)ubg * Tv + t) * Hv + ujg] = hv;                    // plain (cached)
            __hip_atomic_store(hx + ((size_t)(t & 1)) * (Bv * Hv) + (size_t)ubg * Hv + ujg,
                               hv, __ATOMIC_RELAXED, __HIP_MEMORY_SCOPE_AGENT);
            if (t == Tv - 1) {
                hT[ubg * Hv + ujg] = hv;
                cT[ubg * Hv + ujg] = creg;
            }
        }
        // __syncthreads drains every wave's vmcnt (store-ack at MALL) before the flag:
        // this IS the release ordering, minus the L2 flush we don't need.
        __syncthreads();
        if (tid == 0) {
            __hip_atomic_store(flags + bb * 64 + jj, (unsigned)(t + 1),
                               __ATOMIC_RELAXED, __HIP_MEMORY_SCOPE_AGENT);
        }
    }
}

// Fused LayerNorm (unbiased std, eps on std) + 1x1-conv skip, in place on the y region.
// Grid: 2048 blocks x 256 threads; 32 rows/block -> 41 KB LDS -> 3 blocks/CU
// (round-2's 64-row tile was 82 KB -> 1 block/CU -> 1 wave/SIMD, latency-bound).
__global__ void __launch_bounds__(256)
ln_skip(float* __restrict__ y, const float* __restrict__ x,
        const float* __restrict__ gamma, const float* __restrict__ beta,
        const float* __restrict__ conv_w, const float* __restrict__ conv_b)
{
    const int tid = threadIdx.x;
    const size_t r0 = (size_t)blockIdx.x * 32;

    __shared__ float xs[32 * 288];   // x tile [r][kcc*36 + i], chunk 32 + pad 4
    __shared__ float skp[32 * 33];   // skip values for the current 32-col chunk
    __shared__ float mean_s[32], sca_s[32];

    // row stats (8 lanes per row)
    {
        int r = tid >> 3, q = tid & 7;
        const float* hrow = y + (r0 + r) * Hv;
        float sum = 0.f, sq = 0.f;
#pragma unroll
        for (int i = 0; i < 16; ++i) {
            float4 v = *(const float4*)(hrow + (q + i * 8) * 4);
            sum += (v.x + v.y) + (v.z + v.w);
            sq  += v.x*v.x + v.y*v.y + v.z*v.z + v.w*v.w;
        }
        sum += __shfl_xor(sum, 1, 64); sum += __shfl_xor(sum, 2, 64); sum += __shfl_xor(sum, 4, 64);
        sq  += __shfl_xor(sq,  1, 64); sq  += __shfl_xor(sq,  2, 64); sq  += __shfl_xor(sq,  4, 64);
        if (q == 0) {
            float mean = sum * (1.0f / 512.0f);
            float var  = (sq - 512.0f * mean * mean) * (1.0f / 511.0f);
            var = fmaxf(var, 0.0f);
            mean_s[r] = mean;
            sca_s[r]  = 1.0f / (sqrtf(var) + 1e-5f);   // reference: /(std + eps)
        }
    }

    // stage x tile (32 rows x 256)
#pragma unroll
    for (int i = 0; i < 8; ++i) {
        int f = tid + i * 256;
        int r = f >> 6, i4 = f & 63;
        float4 v = *(const float4*)(x + (r0 + r) * INv + i4 * 4);
        *(float4*)(&xs[r * 288 + (i4 >> 3) * 36 + (i4 & 7) * 4]) = v;
    }
    __syncthreads();

    const int c = tid >> 3, kcc = tid & 7;   // 32 cols x 8 k-chunks
    for (int cc = 0; cc < 16; ++cc) {
        const int cg = cc * 32 + c;
        float w[32];
#pragma unroll
        for (int q = 0; q < 8; ++q) {
            float4 v = *(const float4*)(conv_w + (size_t)cg * INv + kcc * 32 + q * 4);
            w[q*4+0] = v.x; w[q*4+1] = v.y; w[q*4+2] = v.z; w[q*4+3] = v.w;
        }
        float cb = conv_b[cg];
        for (int r = 0; r < 32; r += 2) {
            float a0 = 0.f, a1 = 0.f;
#pragma unroll
            for (int q = 0; q < 8; ++q) {
                float4 v0 = *(const float4*)(&xs[r * 288 + kcc * 36 + q * 4]);
                float4 v1 = *(const float4*)(&xs[(r + 1) * 288 + kcc * 36 + q * 4]);
                a0 += v0.x*w[q*4+0] + v0.y*w[q*4+1] + v0.z*w[q*4+2] + v0.w*w[q*4+3];
                a1 += v1.x*w[q*4+0] + v1.y*w[q*4+1] + v1.z*w[q*4+2] + v1.w*w[q*4+3];
            }
            a0 += __shfl_xor(a0, 1, 64); a0 += __shfl_xor(a0, 2, 64); a0 += __shfl_xor(a0, 4, 64);
            a1 += __shfl_xor(a1, 1, 64); a1 += __shfl_xor(a1, 2, 64); a1 += __shfl_xor(a1, 4, 64);
            if (kcc == 0) {
                skp[r * 33 + c]       = a0 + cb;
                skp[(r + 1) * 33 + c] = a1 + cb;
            }
        }
        __syncthreads();
        // output pass for this 32-col chunk (read h then overwrite, same thread)
#pragma unroll
        for (int i = 0; i < 4; ++i) {
            int o = tid + i * 256;
            int r = o >> 5, cl = o & 31;
            int cg2 = cc * 32 + cl;
            size_t idx = (r0 + r) * Hv + cg2;
            float h = y[idx];
            float val = sca_s[r] * gamma[cg2] * (h - mean_s[r]) + beta[cg2] + skp[r * 33 + cl];
            y[idx] = val;
        }
        __syncthreads();
    }
}

extern "C" void kernel_launch(void* const* d_in, const int* in_sizes, int n_in,
                              void* d_out, int out_size, void* d_ws, size_t ws_size,
                              hipStream_t stream) {
    const float* x      = (const float*)d_in[0];
    const float* h0     = (const float*)d_in[1];
    const float* c0     = (const float*)d_in[2];
    const float* W_ih   = (const float*)d_in[3];
    const float* W_hh   = (const float*)d_in[4];
    const float* b_ih   = (const float*)d_in[5];
    const float* b_hh   = (const float*)d_in[6];
    const float* gamma  = (const float*)d_in[7];
    const float* beta   = (const float*)d_in[8];
    const float* conv_w = (const float*)d_in[9];
    const float* conv_b = (const float*)d_in[10];
    float* out = (float*)d_out;

    unsigned* flags = (unsigned*)d_ws;                    // 4 groups x 64 producers
    float*    hx    = (float*)((char*)d_ws + 4096);       // double-buffered h exchange [2][64][512]

    kzero<<<1, 256, 0, stream>>>(flags);
    lstm_persist<<<256, 512, 0, stream>>>(x, h0, c0, W_ih, W_hh, b_ih, b_hh, out, flags, hx);
    ln_skip<<<2048, 256, 0, stream>>>(out, x, gamma, beta, conv_w, conv_b);
}

// Round 9
// 13106.552 us; speedup vs baseline: 1.6925x; 1.6925x over previous
//
#include <hip/hip_runtime.h>
#include <math.h>

#define Bv 64
#define Tv 1024
#define INv 256
#define Hv 512

__device__ __forceinline__ float sigmoidf_(float x) {
    return 1.0f / (1.0f + __expf(-x));
}
__device__ __forceinline__ float tanhf_(float x) {
    float e2 = __expf(-2.0f * fabsf(x));
    float t = (1.0f - e2) / (1.0f + e2);
    return x >= 0.0f ? t : -t;
}

// One LSTM timestep. Grid: 256 blocks (4 batch-groups x 64 unit-groups) x 256 threads.
// Block owns 16 batches x 8 units (32 gate rows). Thread (p, kc): rows {p, p+1024}
// (gate pair), k-chunk kc of K=768 (16 x-cols + 32 h-cols). 2 rows/thread halves
// LDS read traffic (8 MAC per 16B ds_read). No cross-block sync: h(t-1) comes from
// the previous dispatch via the out array; AQL dispatch fences give coherence.
__global__ void __launch_bounds__(256, 1)
lstm_step(const float* __restrict__ x_t,    // x + t*INv (batch stride Tv*INv)
          const float* __restrict__ hprev,  // batch stride hstride
          size_t hstride,
          const float* __restrict__ W_ih, const float* __restrict__ W_hh,
          const float* __restrict__ b_ih, const float* __restrict__ b_hh,
          float* __restrict__ c_buf,        // [64][512], owned elementwise per block
          float* __restrict__ hout,         // out + t*Hv (batch stride Tv*Hv)
          float* __restrict__ hT, float* __restrict__ cT, int last)
{
    const int tid = threadIdx.x;
    const int bb  = blockIdx.x >> 6;    // batch group 0..3
    const int jj  = blockIdx.x & 63;    // unit group 0..63
    const int p   = tid >> 4;           // row-pair id 0..15
    const int kc  = tid & 15;           // k-chunk 0..15

    // rows: lg0 = p (gates 0-1), lg1 = p+16 (gates 2-3)  => rowB = rowA + 1024
    const int rowA = (p >> 3) * Hv + jj * 8 + (p & 7);

    __shared__ float xs[16 * 320];    // x tile: [b][kc*20 + i], chunk 16 + pad 4
    __shared__ float hsh[16 * 576];   // h tile: [b][kc*36 + i], chunk 32 + pad 4
    __shared__ float gts[16 * 33];    // reduced gates [b][lg]

    // ---- weight slices into registers (L2-resident across launches) ----
    float wihA[16], wihB[16], whhA[32], whhB[32];
#pragma unroll
    for (int q = 0; q < 4; ++q) {
        float4 v = *(const float4*)(W_ih + (size_t)rowA * INv + kc * 16 + q * 4);
        wihA[q*4+0]=v.x; wihA[q*4+1]=v.y; wihA[q*4+2]=v.z; wihA[q*4+3]=v.w;
        float4 w = *(const float4*)(W_ih + (size_t)(rowA + 1024) * INv + kc * 16 + q * 4);
        wihB[q*4+0]=w.x; wihB[q*4+1]=w.y; wihB[q*4+2]=w.z; wihB[q*4+3]=w.w;
    }
#pragma unroll
    for (int q = 0; q < 8; ++q) {
        float4 v = *(const float4*)(W_hh + (size_t)rowA * Hv + kc * 32 + q * 4);
        whhA[q*4+0]=v.x; whhA[q*4+1]=v.y; whhA[q*4+2]=v.z; whhA[q*4+3]=v.w;
        float4 w = *(const float4*)(W_hh + (size_t)(rowA + 1024) * Hv + kc * 32 + q * 4);
        whhB[q*4+0]=w.x; whhB[q*4+1]=w.y; whhB[q*4+2]=w.z; whhB[q*4+3]=w.w;
    }
    const float biasA = b_ih[rowA] + b_hh[rowA];
    const float biasB = b_ih[rowA + 1024] + b_hh[rowA + 1024];

    // ---- stage x tile: 16 b x 256 floats ----
#pragma unroll
    for (int it = 0; it < 4; ++it) {
        int f = tid + it * 256;          // [0,1024) f4 index
        int b = f >> 6, i4 = f & 63;
        float4 v = *(const float4*)(x_t + (size_t)(bb*16 + b) * ((size_t)Tv * INv) + i4 * 4);
        *(float4*)(&xs[b * 320 + (i4 >> 2) * 20 + (i4 & 3) * 4]) = v;
    }
    // ---- stage h tile: 16 b x 512 floats ----
#pragma unroll
    for (int it = 0; it < 8; ++it) {
        int f = tid + it * 256;          // [0,2048) f4 index
        int b = f >> 7, i4 = f & 127;
        float4 v = *(const float4*)(hprev + (size_t)(bb*16 + b) * hstride + i4 * 4);
        *(float4*)(&hsh[b * 576 + (i4 >> 3) * 36 + (i4 & 7) * 4]) = v;
    }
    __syncthreads();

    float accA[16], accB[16];
#pragma unroll
    for (int b = 0; b < 16; ++b) { accA[b] = 0.0f; accB[b] = 0.0f; }

    // x part: 4 f4-chunks per thread
#pragma unroll
    for (int i4 = 0; i4 < 4; ++i4) {
#pragma unroll
        for (int b = 0; b < 16; ++b) {
            float4 v = *(const float4*)(&xs[b * 320 + kc * 20 + i4 * 4]);
            accA[b] += v.x*wihA[i4*4+0] + v.y*wihA[i4*4+1] + v.z*wihA[i4*4+2] + v.w*wihA[i4*4+3];
            accB[b] += v.x*wihB[i4*4+0] + v.y*wihB[i4*4+1] + v.z*wihB[i4*4+2] + v.w*wihB[i4*4+3];
        }
    }
    // h part: 8 f4-chunks per thread
#pragma unroll
    for (int i4 = 0; i4 < 8; ++i4) {
#pragma unroll
        for (int b = 0; b < 16; ++b) {
            float4 v = *(const float4*)(&hsh[b * 576 + kc * 36 + i4 * 4]);
            accA[b] += v.x*whhA[i4*4+0] + v.y*whhA[i4*4+1] + v.z*whhA[i4*4+2] + v.w*whhA[i4*4+3];
            accB[b] += v.x*whhB[i4*4+0] + v.y*whhB[i4*4+1] + v.z*whhB[i4*4+2] + v.w*whhB[i4*4+3];
        }
    }

    // reduce partial dots across the 16 kc lanes (lane bits 0..3)
#pragma unroll
    for (int m = 1; m <= 8; m <<= 1) {
#pragma unroll
        for (int b = 0; b < 16; ++b) {
            accA[b] += __shfl_xor(accA[b], m, 64);
            accB[b] += __shfl_xor(accB[b], m, 64);
        }
    }
    if (kc == 0) {
#pragma unroll
        for (int b = 0; b < 16; ++b) {
            gts[b * 33 + p]      = accA[b] + biasA;
            gts[b * 33 + p + 16] = accB[b] + biasB;
        }
    }
    __syncthreads();

    // gate nonlinearities + state update (torch gate order i,f,g,o)
    if (tid < 128) {
        const int ub = tid >> 3, uj = tid & 7;
        const int ubg = bb * 16 + ub, ujg = jj * 8 + uj;
        float gi = gts[ub * 33 +      uj];
        float gf = gts[ub * 33 +  8 + uj];
        float gg = gts[ub * 33 + 16 + uj];
        float go = gts[ub * 33 + 24 + uj];
        float iv = sigmoidf_(gi), fv = sigmoidf_(gf);
        float gv = tanhf_(gg),    ov = sigmoidf_(go);
        float c  = c_buf[ubg * Hv + ujg];
        c = fv * c + iv * gv;
        float hv = ov * tanhf_(c);
        c_buf[ubg * Hv + ujg] = c;
        hout[(size_t)ubg * ((size_t)Tv * Hv) + ujg] = hv;
        if (last) {
            hT[ubg * Hv + ujg] = hv;
            cT[ubg * Hv + ujg] = c;
        }
    }
}

// Fused LayerNorm (unbiased std, eps on std) + 1x1-conv skip, in place on the y region.
// Grid: 2048 blocks x 256 threads; 32 rows/block -> 41 KB LDS -> 3 blocks/CU.
__global__ void __launch_bounds__(256)
ln_skip(float* __restrict__ y, const float* __restrict__ x,
        const float* __restrict__ gamma, const float* __restrict__ beta,
        const float* __restrict__ conv_w, const float* __restrict__ conv_b)
{
    const int tid = threadIdx.x;
    const size_t r0 = (size_t)blockIdx.x * 32;

    __shared__ float xs[32 * 288];   // x tile [r][kcc*36 + i], chunk 32 + pad 4
    __shared__ float skp[32 * 33];   // skip values for the current 32-col chunk
    __shared__ float mean_s[32], sca_s[32];

    // row stats (8 lanes per row)
    {
        int r = tid >> 3, q = tid & 7;
        const float* hrow = y + (r0 + r) * Hv;
        float sum = 0.f, sq = 0.f;
#pragma unroll
        for (int i = 0; i < 16; ++i) {
            float4 v = *(const float4*)(hrow + (q + i * 8) * 4);
            sum += (v.x + v.y) + (v.z + v.w);
            sq  += v.x*v.x + v.y*v.y + v.z*v.z + v.w*v.w;
        }
        sum += __shfl_xor(sum, 1, 64); sum += __shfl_xor(sum, 2, 64); sum += __shfl_xor(sum, 4, 64);
        sq  += __shfl_xor(sq,  1, 64); sq  += __shfl_xor(sq,  2, 64); sq  += __shfl_xor(sq,  4, 64);
        if (q == 0) {
            float mean = sum * (1.0f / 512.0f);
            float var  = (sq - 512.0f * mean * mean) * (1.0f / 511.0f);
            var = fmaxf(var, 0.0f);
            mean_s[r] = mean;
            sca_s[r]  = 1.0f / (sqrtf(var) + 1e-5f);   // reference: /(std + eps)
        }
    }

    // stage x tile (32 rows x 256)
#pragma unroll
    for (int i = 0; i < 8; ++i) {
        int f = tid + i * 256;
        int r = f >> 6, i4 = f & 63;
        float4 v = *(const float4*)(x + (r0 + r) * INv + i4 * 4);
        *(float4*)(&xs[r * 288 + (i4 >> 3) * 36 + (i4 & 7) * 4]) = v;
    }
    __syncthreads();

    const int c = tid >> 3, kcc = tid & 7;   // 32 cols x 8 k-chunks
    for (int cc = 0; cc < 16; ++cc) {
        const int cg = cc * 32 + c;
        float w[32];
#pragma unroll
        for (int q = 0; q < 8; ++q) {
            float4 v = *(const float4*)(conv_w + (size_t)cg * INv + kcc * 32 + q * 4);
            w[q*4+0] = v.x; w[q*4+1] = v.y; w[q*4+2] = v.z; w[q*4+3] = v.w;
        }
        float cb = conv_b[cg];
        for (int r = 0; r < 32; r += 2) {
            float a0 = 0.f, a1 = 0.f;
#pragma unroll
            for (int q = 0; q < 8; ++q) {
                float4 v0 = *(const float4*)(&xs[r * 288 + kcc * 36 + q * 4]);
                float4 v1 = *(const float4*)(&xs[(r + 1) * 288 + kcc * 36 + q * 4]);
                a0 += v0.x*w[q*4+0] + v0.y*w[q*4+1] + v0.z*w[q*4+2] + v0.w*w[q*4+3];
                a1 += v1.x*w[q*4+0] + v1.y*w[q*4+1] + v1.z*w[q*4+2] + v1.w*w[q*4+3];
            }
            a0 += __shfl_xor(a0, 1, 64); a0 += __shfl_xor(a0, 2, 64); a0 += __shfl_xor(a0, 4, 64);
            a1 += __shfl_xor(a1, 1, 64); a1 += __shfl_xor(a1, 2, 64); a1 += __shfl_xor(a1, 4, 64);
            if (kcc == 0) {
                skp[r * 33 + c]       = a0 + cb;
                skp[(r + 1) * 33 + c] = a1 + cb;
            }
        }
        __syncthreads();
        // output pass for this 32-col chunk (read h then overwrite, same thread)
#pragma unroll
        for (int i = 0; i < 4; ++i) {
            int o = tid + i * 256;
            int r = o >> 5, cl = o & 31;
            int cg2 = cc * 32 + cl;
            size_t idx = (r0 + r) * Hv + cg2;
            float h = y[idx];
            float val = sca_s[r] * gamma[cg2] * (h - mean_s[r]) + beta[cg2] + skp[r * 33 + cl];
            y[idx] = val;
        }
        __syncthreads();
    }
}

extern "C" void kernel_launch(void* const* d_in, const int* in_sizes, int n_in,
                              void* d_out, int out_size, void* d_ws, size_t ws_size,
                              hipStream_t stream) {
    const float* x      = (const float*)d_in[0];
    const float* h0     = (const float*)d_in[1];
    const float* c0     = (const float*)d_in[2];
    const float* W_ih   = (const float*)d_in[3];
    const float* W_hh   = (const float*)d_in[4];
    const float* b_ih   = (const float*)d_in[5];
    const float* b_hh   = (const float*)d_in[6];
    const float* gamma  = (const float*)d_in[7];
    const float* beta   = (const float*)d_in[8];
    const float* conv_w = (const float*)d_in[9];
    const float* conv_b = (const float*)d_in[10];
    float* out = (float*)d_out;

    float* c_buf = (float*)d_ws;                          // [64][512] cell state
    float* hT = out + (size_t)Bv * Tv * Hv;
    float* cT = hT + (size_t)Bv * Hv;

    // init cell state (async d2d is graph-capture safe)
    hipMemcpyAsync(c_buf, c0, (size_t)Bv * Hv * sizeof(float),
                   hipMemcpyDeviceToDevice, stream);

    for (int t = 0; t < Tv; ++t) {
        const float* hprev = (t == 0) ? h0 : (out + (size_t)(t - 1) * Hv);
        size_t hstride = (t == 0) ? (size_t)Hv : (size_t)Tv * Hv;
        lstm_step<<<256, 256, 0, stream>>>(x + (size_t)t * INv, hprev, hstride,
                                           W_ih, W_hh, b_ih, b_hh, c_buf,
                                           out + (size_t)t * Hv, hT, cT,
                                           (t == Tv - 1) ? 1 : 0);
    }

    ln_skip<<<2048, 256, 0, stream>>>(out, x, gamma, beta, conv_w, conv_b);
}